// Round 5
// baseline (328079.761 us; speedup 1.0000x reference)
//
#include <hip/hip_runtime.h>
#include <stdint.h>

// Problem constants (B,S,I,H,O) = (64, 2048, 256, 512, 256), all fp32.
#define Bn 64
#define Sn 2048
#define In 256
#define Hn 512
#define On 256
#define KS 384   // front-chain length (thread A); back = Hn - KS = 128 (thread B)
#define NB 4     // batches per block (multi-batch amortization)
#define NG 16    // batch groups (NG * NB = Bn); grid = NG*4 = 64 blocks

// ---------------------------------------------------------------------------
// BIT-EXACT constraint (proven, absmax 0.0): per output element the
// arithmetic must be exactly
//   xacc = fma-chain_{i=0..255 asc}(xs[i], Wxh[i][j]);  xw = xacc + bias_h[j]
//   hacc = fma-chain_{k=0..511 asc}(hs[k], Whh[k][j]);  u  = xw + hacc
//   h' = xla_tanh(u);   y = fma-chain_k(h[k],Why[k][o]) + bias_y[o]
// Interleaving chains ACROSS batches does not alter any per-batch FP order.
//
// SYNC v6. Evidence ledger:
//  v0 (33.7ms = 16.4us/step): publish -> barrier(vmcnt drain) -> release
//     flag -> acquire spins -> relaxed 4B payload loads. FETCH 230MB
//     (spins ~never iterate). PROVEN fast-enough & correct.
//  v2-v5 (~120ms): tagged relaxed u64 words, four poll topologies, ALL
//     converge to ~55us/step + FETCH ~15GB -> relaxed-atomic tagged
//     visibility path is itself slow; topology irrelevant. Abandoned.
// v6 = v0 primitives EXACTLY, restructured for amortization:
//   * 64 blocks = 16 groups x 4 slices; each block runs NB=4 batches
//     (weights are batch-independent -> same register budget serves 4x).
//   * ONE protocol round per step covers 4 batches (per-group flags;
//     12 payload loads issued back-to-back).
//   * chains interleaved 2-wide across batches: A-cost = NB*384 FMA
//     ISSUE-bound (~3072cy) instead of latency-bound.
//   * 4x fewer spinning blocks than v0.
// Overwrite safety (parity slots), transitive, as in v0: publisher at
// step t passed its own phase-1 spins (flags >= t) => all 3 siblings
// finished step t-1 => their reads of h_{t-1} (the slot being
// overwritten) retired before their barrier #0. Flags re-poisoned to
// 0xAA.. = negative -> never >= t (t>=1) -> no memset needed; payload
// slots are never read before their flag is set.
// Partition per block: 256 threads = 128 A (384 Whh regs, chain k<384)
// + 128 B (256 Wxh + 128 Whh regs, xacc + k>=384 + tanh + publish).
// ~430 regs/thread -> 1 block/CU; 64 blocks always co-resident.
// ---------------------------------------------------------------------------

__device__ __forceinline__ float xla_tanh(float x) {
    const float ax = __builtin_fabsf(x);
    float xc = fmaxf(-7.99881172180175781f, fminf(7.99881172180175781f, x));
    const float x2 = xc * xc;
    float p = fmaf(x2, -2.76076847742355e-16f, 2.00018790482477e-13f);
    p = fmaf(x2, p, -8.60467152213735e-11f);
    p = fmaf(x2, p, 5.12229709037114e-08f);
    p = fmaf(x2, p, 1.48572235717979e-05f);
    p = fmaf(x2, p, 6.37261928875436e-04f);
    p = fmaf(x2, p, 4.89352455891786e-03f);
    p = xc * p;
    float q = fmaf(x2, 1.19825839466702e-06f, 1.18534705686654e-04f);
    q = fmaf(x2, q, 2.26843463243900e-03f);
    q = fmaf(x2, q, 4.89352518554385e-03f);
    return ax < 0.0004f ? x : p / q;
}

__device__ __forceinline__ float pay_ld(const float* p) {
    return __hip_atomic_load(p, __ATOMIC_RELAXED, __HIP_MEMORY_SCOPE_AGENT);
}
__device__ __forceinline__ void pay_st(float* p, float v) {
    __hip_atomic_store(p, v, __ATOMIC_RELAXED, __HIP_MEMORY_SCOPE_AGENT);
}

__global__ __launch_bounds__(256, 1) void rnn_scan(const float* __restrict__ x,
                                                   const float* __restrict__ Wxh,
                                                   const float* __restrict__ Whh,
                                                   const float* __restrict__ bias_h,
                                                   float* __restrict__ hpub,
                                                   int* __restrict__ flags,
                                                   float* __restrict__ hlast) {
    const int blk = blockIdx.x;      // 0..63
    const int g = blk >> 2;          // batch group 0..15
    const int s = blk & 3;           // column-slice 0..3
    const int tid = threadIdx.x;
    const int c = tid & 127;         // column within slice
    const bool isA = tid < 128;      // wave-uniform role split
    const int j = s * 128 + c;       // global column
    const int b0 = g * NB;           // first batch of this group

    __shared__ float hs[NB][2][Hn];   // per-batch double-buffered h
    __shared__ float xs[NB][2][In];   // per-batch double-buffered x row
    __shared__ float pacc[NB][128];   // A->B chain-accumulator handoff

    // Weight registers (384 floats/thread, coalesced: lanes = consecutive j).
    // Shared across all NB batches — this is the amortization lever.
    float W0[KS];
    if (isA) {
#pragma unroll
        for (int k = 0; k < KS; ++k) W0[k] = Whh[(size_t)k * Hn + j];
    } else {
#pragma unroll
        for (int i = 0; i < In; ++i) W0[i] = Wxh[(size_t)i * Hn + j];
#pragma unroll
        for (int k = 0; k < 128; ++k) W0[In + k] = Whh[(size_t)(KS + k) * Hn + j];
    }
    const float bh = isA ? 0.f : bias_h[j];

#pragma unroll
    for (int mi = 0; mi < NB; ++mi) {
        hs[mi][0][tid] = 0.f;                                    // h_0 = 0
        hs[mi][0][tid + 256] = 0.f;
        xs[mi][0][tid] = x[(size_t)(b0 + mi) * Sn * In + tid];   // row 0
    }
    __syncthreads();

    // Payload: hpub[g][parity][slice][mi][128] floats.
    float* const gpub = hpub + (size_t)g * (2 * 4 * NB * 128);
    // Flags: one 64B line per (group,slice): flags[(g*4+s)*16], monotonic t.
    int* const gflag = flags + g * 4 * 16;

    float hnv[NB] = {0.f, 0.f, 0.f, 0.f};
    float xwv[NB];

    for (int t = 0; t < Sn; ++t) {
        const int p = t & 1;

        // ------------------- PHASE 1 (A: stage | B: xacc) -------------------
        if (isA) {
            if (t > 0) {
                // acquire-spin the needed remote flags (v0-proven pattern;
                // wave-broadcast same-address loads, s_sleep pacing)
#pragma unroll
                for (int r = 0; r < 3; ++r) {
                    if (r != s) {
                        const int* f = gflag + r * 16;
                        while (__hip_atomic_load(f, __ATOMIC_ACQUIRE,
                                                 __HIP_MEMORY_SCOPE_AGENT) < t)
                            __builtin_amdgcn_s_sleep(2);
                    }
                }
                // stage all payloads: issue every load back-to-back
                // (independent -> latencies overlap), then LDS-write
                float tmp[3][NB];
#pragma unroll
                for (int r = 0; r < 3; ++r) {
                    if (r != s) {
#pragma unroll
                        for (int mi = 0; mi < NB; ++mi)
                            tmp[r][mi] = pay_ld(gpub +
                                (((size_t)p * 4 + r) * NB + mi) * 128 + c);
                    }
                }
#pragma unroll
                for (int r = 0; r < 3; ++r) {
                    if (r != s) {
#pragma unroll
                        for (int mi = 0; mi < NB; ++mi)
                            hs[mi][p][r * 128 + c] = tmp[r][mi];
                    }
                }
            }
        } else {
            // prefetch next x rows first (hide HBM latency under xacc)
            float xn0[NB], xn1[NB];
            if (t + 1 < Sn) {
#pragma unroll
                for (int mi = 0; mi < NB; ++mi) {
                    xn0[mi] = x[((size_t)(b0 + mi) * Sn + t + 1) * In + c];
                    xn1[mi] = x[((size_t)(b0 + mi) * Sn + t + 1) * In + 128 + c];
                }
            }
            // xacc, 2-wide batch interleave (per-batch i-order unchanged)
#pragma unroll
            for (int pr = 0; pr < NB / 2; ++pr) {
                float a0 = 0.f, a1 = 0.f;
                const float4* x40 = (const float4*)&xs[2 * pr + 0][p][0];
                const float4* x41 = (const float4*)&xs[2 * pr + 1][p][0];
#pragma unroll
                for (int q = 0; q < In / 4; ++q) {
                    float4 u = x40[q], v = x41[q];
                    a0 = fmaf(u.x, W0[4 * q + 0], a0); a1 = fmaf(v.x, W0[4 * q + 0], a1);
                    a0 = fmaf(u.y, W0[4 * q + 1], a0); a1 = fmaf(v.y, W0[4 * q + 1], a1);
                    a0 = fmaf(u.z, W0[4 * q + 2], a0); a1 = fmaf(v.z, W0[4 * q + 2], a1);
                    a0 = fmaf(u.w, W0[4 * q + 3], a0); a1 = fmaf(v.w, W0[4 * q + 3], a1);
                }
                xwv[2 * pr + 0] = a0 + bh;
                xwv[2 * pr + 1] = a1 + bh;
            }
            // B stages slice 3 (its chain range k in [384,512)) after xacc —
            // the xacc window gives the publisher time, v0-style
            if (t > 0 && s != 3) {
                const int* f3 = gflag + 3 * 16;
                while (__hip_atomic_load(f3, __ATOMIC_ACQUIRE,
                                         __HIP_MEMORY_SCOPE_AGENT) < t)
                    __builtin_amdgcn_s_sleep(2);
                float t3[NB];
#pragma unroll
                for (int mi = 0; mi < NB; ++mi)
                    t3[mi] = pay_ld(gpub + (((size_t)p * 4 + 3) * NB + mi) * 128 + c);
#pragma unroll
                for (int mi = 0; mi < NB; ++mi)
                    hs[mi][p][KS + c] = t3[mi];
            }
            if (t + 1 < Sn) {
#pragma unroll
                for (int mi = 0; mi < NB; ++mi) {
                    xs[mi][1 - p][c] = xn0[mi];
                    xs[mi][1 - p][128 + c] = xn1[mi];
                }
            }
        }
        __syncthreads();   // #0: hs[*][p] complete (remote staged, local t-1)

        // ------------------- PHASE 2 (A: hacc prefix chains) ----------------
        if (isA) {
            // k = 0..383 ascending, single accumulator per batch (exact
            // order); 2-wide batch interleave hides FMA dep latency
#pragma unroll
            for (int pr = 0; pr < NB / 2; ++pr) {
                float a0 = 0.f, a1 = 0.f;
                const float4* h40 = (const float4*)&hs[2 * pr + 0][p][0];
                const float4* h41 = (const float4*)&hs[2 * pr + 1][p][0];
#pragma unroll
                for (int q = 0; q < KS / 4; ++q) {
                    float4 u = h40[q], v = h41[q];
                    a0 = fmaf(u.x, W0[4 * q + 0], a0); a1 = fmaf(v.x, W0[4 * q + 0], a1);
                    a0 = fmaf(u.y, W0[4 * q + 1], a0); a1 = fmaf(v.y, W0[4 * q + 1], a1);
                    a0 = fmaf(u.z, W0[4 * q + 2], a0); a1 = fmaf(v.z, W0[4 * q + 2], a1);
                    a0 = fmaf(u.w, W0[4 * q + 3], a0); a1 = fmaf(v.w, W0[4 * q + 3], a1);
                }
                pacc[2 * pr + 0][c] = a0;
                pacc[2 * pr + 1][c] = a1;
            }
        }
        __syncthreads();   // #1: pacc ready

        // ------------ PHASE 3 (B: suffix + tanh + publish) ------------------
        if (!isA) {
#pragma unroll
            for (int pr = 0; pr < NB / 2; ++pr) {
                float a0 = pacc[2 * pr + 0][c], a1 = pacc[2 * pr + 1][c];
                const float4* h40 = (const float4*)&hs[2 * pr + 0][p][KS];
                const float4* h41 = (const float4*)&hs[2 * pr + 1][p][KS];
#pragma unroll
                for (int q = 0; q < 32; ++q) {
                    float4 u = h40[q], v = h41[q];
                    a0 = fmaf(u.x, W0[In + 4 * q + 0], a0); a1 = fmaf(v.x, W0[In + 4 * q + 0], a1);
                    a0 = fmaf(u.y, W0[In + 4 * q + 1], a0); a1 = fmaf(v.y, W0[In + 4 * q + 1], a1);
                    a0 = fmaf(u.z, W0[In + 4 * q + 2], a0); a1 = fmaf(v.z, W0[In + 4 * q + 2], a1);
                    a0 = fmaf(u.w, W0[In + 4 * q + 3], a0); a1 = fmaf(v.w, W0[In + 4 * q + 3], a1);
                }
                const float u0 = xwv[2 * pr + 0] + a0;   // exact association
                const float u1 = xwv[2 * pr + 1] + a1;
                const float h0 = xla_tanh(u0);
                const float h1 = xla_tanh(u1);
                hnv[2 * pr + 0] = h0; hnv[2 * pr + 1] = h1;
                hs[2 * pr + 0][1 - p][j] = h0;           // local slice for t+1
                hs[2 * pr + 1][1 - p][j] = h1;
                if (t + 1 < Sn) {
                    pay_st(gpub + (((size_t)(1 - p) * 4 + s) * NB + 2 * pr + 0) * 128 + c, h0);
                    pay_st(gpub + (((size_t)(1 - p) * 4 + s) * NB + 2 * pr + 1) * 128 + c, h1);
                }
            }
        }
        __syncthreads();   // #2: drains vmcnt -> ALL publish stores complete

        if (tid == 0 && t + 1 < Sn)
            __hip_atomic_store(gflag + s * 16, t + 1, __ATOMIC_RELEASE,
                               __HIP_MEMORY_SCOPE_AGENT);
    }

    if (!isA) {
#pragma unroll
        for (int mi = 0; mi < NB; ++mi)
            hlast[(size_t)(b0 + mi) * Hn + j] = hnv[mi];
    }
}

// ---------------------------------------------------------------------------
// y[b][o] = fma-chain_k(h_last[b][k]*Why[k][o]) + bias_y[o]  (unchanged, exact)
// ---------------------------------------------------------------------------
__global__ __launch_bounds__(256) void out_gemm(const float* __restrict__ hlast,
                                                const float* __restrict__ Why,
                                                const float* __restrict__ bias_y,
                                                float* __restrict__ y) {
    const int b = blockIdx.x, o = threadIdx.x;
    __shared__ float hs[Hn];
    hs[o] = hlast[(size_t)b * Hn + o];
    hs[o + 256] = hlast[(size_t)b * Hn + o + 256];
    __syncthreads();
    float acc = 0.0f;
#pragma unroll 8
    for (int k = 0; k < Hn; ++k)
        acc = fmaf(hs[k], Why[(size_t)k * On + o], acc);
    y[(size_t)b * On + o] = acc + bias_y[o];
}

// ---------------------------------------------------------------------------
extern "C" void kernel_launch(void* const* d_in, const int* in_sizes, int n_in,
                              void* d_out, int out_size, void* d_ws, size_t ws_size,
                              hipStream_t stream) {
    // Map inputs by size (x=33554432, Whh=262144, Wxh/Why=131072 in order,
    // bias_h=512, bias_y=256).
    const float *x = nullptr, *Wxh = nullptr, *Whh = nullptr, *Why = nullptr,
                *bias_h = nullptr, *bias_y = nullptr;
    for (int i = 0; i < n_in; ++i) {
        const float* p = (const float*)d_in[i];
        const int sz = in_sizes[i];
        if (sz == Bn * Sn * In) x = p;
        else if (sz == Hn * Hn) Whh = p;
        else if (sz == In * Hn) { if (!Wxh) Wxh = p; else Why = p; }
        else if (sz == Hn) bias_h = p;
        else if (sz == On) bias_y = p;
    }
    float* y = (float*)d_out;

    // workspace: hpub (16 groups * 2 * 4 * 4 * 128 floats = 256 KB) +
    // flags (64 * 16 ints = 4 KB) + hlast (128 KB). NO memset: 0xAA poison
    // decodes to negative flag values (never >= t for t >= 1), and payload
    // slots are never read before their flag is set.
    char* ws = (char*)d_ws;
    float* hpub = (float*)ws;
    size_t hpub_bytes = (size_t)NG * 2 * 4 * NB * 128 * sizeof(float);
    int* flags = (int*)(ws + hpub_bytes);
    size_t flag_bytes = (size_t)NG * 4 * 16 * sizeof(int);
    float* hlast = (float*)(ws + hpub_bytes + flag_bytes);

    rnn_scan<<<dim3(NG * 4), dim3(256), 0, stream>>>(x, Wxh, Whh, bias_h,
                                                     hpub, flags, hlast);
    out_gemm<<<dim3(Bn), dim3(On), 0, stream>>>(hlast, Why, bias_y, y);
}

// Round 6
// 30003.616 us; speedup vs baseline: 10.9347x; 10.9347x over previous
//
#include <hip/hip_runtime.h>
#include <stdint.h>

// Problem constants (B,S,I,H,O) = (64, 2048, 256, 512, 256), all fp32.
#define Bn 64
#define Sn 2048
#define In 256
#define Hn 512
#define On 256
#define TT 16      // timesteps per xw-precompute block (Sn % TT == 0)
#define CH 32      // Whh rows per stream chunk in the scan (512/CH = 16 chunks)

// ---------------------------------------------------------------------------
// BIT-EXACT constraint (proven, absmax 0.0): per output element
//   xacc = fma-chain_{i=0..255 asc}(x[i], Wxh[i][j]);  xw = xacc + bias_h[j]
//   hacc = fma-chain_{k=0..511 asc}(h[k], Whh[k][j]);  u  = xw + hacc
//   h' = xla_tanh(u);   y = fma-chain_k(h[k],Why[k][o]) + bias_y[o]
//
// DESIGN v7 — evidence ledger:
//  v0 (33.7ms): 4 blocks/batch, weights in VGPRs, cross-block rendezvous
//     every step -> 16.4us/step, ~all protocol latency (VALUBusy 5.7%).
//  v2-v5 (~120ms): every tagged/polling protocol variant saturates the
//     agent-scope coherent path; topology irrelevant.
//  v6 (328ms): multi-batch amortization -> register spill (WRITE 49.7GB =
//     W0[384] spilled/refilled per step). Register budget is a cliff.
// Conclusion: the per-step protocol is structural to register-resident
// weights (Whh = 2 full CU register files -> >=3-block split -> rendezvous).
// v7 removes inter-block communication entirely:
//   * xw = x@Wxh + bias_h hoisted into a one-shot GEMM (bit-exact chain),
//     stored in workspace (256MB; fallback template if ws too small).
//   * scan: ONE block per batch (64 blocks, 8/XCD round-robin), 256
//     threads, thread owns 2 adjacent columns. Whh (1MB) STREAMED from
//     the XCD-resident L2 every step via float2 loads (coalesced 2KB/row),
//     4-buffer distance-2 software pipeline; 16 chunks % 4 bufs == 0 so
//     the rotation is steady-state ACROSS steps (no per-step prologue
//     latency; Whh addresses repeat every step).
//   * h lives in LDS only (broadcast ds_read_b128); ONE barrier per step.
//   * ~285 VGPR by construction — far from the v6 spill cliff.
//   * No atomics, no flags, no fences, no memset.
// Issue floor/step: 16 x (32 ld + 8 ds + 64 fma) ~ 3400cy ~ 1.4us.
// ---------------------------------------------------------------------------

__device__ __forceinline__ float xla_tanh(float x) {
    const float ax = __builtin_fabsf(x);
    float xc = fmaxf(-7.99881172180175781f, fminf(7.99881172180175781f, x));
    const float x2 = xc * xc;
    float p = fmaf(x2, -2.76076847742355e-16f, 2.00018790482477e-13f);
    p = fmaf(x2, p, -8.60467152213735e-11f);
    p = fmaf(x2, p, 5.12229709037114e-08f);
    p = fmaf(x2, p, 1.48572235717979e-05f);
    p = fmaf(x2, p, 6.37261928875436e-04f);
    p = fmaf(x2, p, 4.89352455891786e-03f);
    p = xc * p;
    float q = fmaf(x2, 1.19825839466702e-06f, 1.18534705686654e-04f);
    q = fmaf(x2, q, 2.26843463243900e-03f);
    q = fmaf(x2, q, 4.89352518554385e-03f);
    return ax < 0.0004f ? x : p / q;
}

// ---------------------------------------------------------------------------
// xw[b][t][j] = bias_h[j] + fma-chain_{i asc}(x[b][t][i], Wxh[i][j])
// Exact order: i ascending, single accumulator, bias added AFTER the chain
// (byte-identical to the proven in-scan xacc).
// ---------------------------------------------------------------------------
__global__ __launch_bounds__(512) void xw_gemm(const float* __restrict__ x,
                                               const float* __restrict__ Wxh,
                                               const float* __restrict__ bias_h,
                                               float* __restrict__ xw) {
    const int b = blockIdx.x >> 7;               // Sn/TT = 128 tiles per batch
    const int t0 = (blockIdx.x & 127) * TT;
    const int j = threadIdx.x;                   // output column 0..511
    __shared__ float xl[TT][In];

    const float4* xsrc = (const float4*)(x + ((size_t)b * Sn + t0) * In);
    float4* xdst = (float4*)&xl[0][0];
    for (int u = j; u < TT * In / 4; u += 512) xdst[u] = xsrc[u];
    __syncthreads();

    float acc[TT];
#pragma unroll
    for (int m = 0; m < TT; ++m) acc[m] = 0.f;

    for (int i = 0; i < In; i += 4) {
        const float w0 = Wxh[(size_t)(i + 0) * Hn + j];   // coalesced across j
        const float w1 = Wxh[(size_t)(i + 1) * Hn + j];
        const float w2 = Wxh[(size_t)(i + 2) * Hn + j];
        const float w3 = Wxh[(size_t)(i + 3) * Hn + j];
#pragma unroll
        for (int m = 0; m < TT; ++m) {
            const float4 xv = *(const float4*)&xl[m][i];  // LDS broadcast
            float a = acc[m];
            a = fmaf(xv.x, w0, a);
            a = fmaf(xv.y, w1, a);
            a = fmaf(xv.z, w2, a);
            a = fmaf(xv.w, w3, a);
            acc[m] = a;
        }
    }
    const float bh = bias_h[j];
#pragma unroll
    for (int m = 0; m < TT; ++m)
        xw[((size_t)b * Sn + t0 + m) * Hn + j] = acc[m] + bh;
}

// ---------------------------------------------------------------------------
// Scan: one block per batch, Whh streamed. CHUNKW = wrapped prefetch
// (PRE path steady-state); CHUNKL = linear prefetch with guard (fallback).
// Only buffer NAMES vary per call -> all register arrays statically indexed
// (v6 lesson / rule #20: dynamic indexing => scratch).
// ---------------------------------------------------------------------------
#define CHUNKW(WP, HP4, CUR, NXT, C)                                          \
    {                                                                         \
        const int kpre_ = (((C) + 2) & 15) * CH;                              \
        _Pragma("unroll") for (int u_ = 0; u_ < CH; ++u_)                     \
            NXT[u_] = (WP)[(size_t)(kpre_ + u_) * 256];                       \
        _Pragma("unroll") for (int u_ = 0; u_ < CH; u_ += 4) {                \
            const float4 hv_ = (HP4)[((C) * CH + u_) >> 2];                   \
            a0 = fmaf(hv_.x, CUR[u_ + 0].x, a0); a1 = fmaf(hv_.x, CUR[u_ + 0].y, a1); \
            a0 = fmaf(hv_.y, CUR[u_ + 1].x, a0); a1 = fmaf(hv_.y, CUR[u_ + 1].y, a1); \
            a0 = fmaf(hv_.z, CUR[u_ + 2].x, a0); a1 = fmaf(hv_.z, CUR[u_ + 2].y, a1); \
            a0 = fmaf(hv_.w, CUR[u_ + 3].x, a0); a1 = fmaf(hv_.w, CUR[u_ + 3].y, a1); \
        }                                                                     \
    }

#define CHUNKL(WP, HP4, CUR, NXT, C, N, A0, A1)                               \
    {                                                                         \
        if ((C) + 2 < (N)) {                                                  \
            _Pragma("unroll") for (int u_ = 0; u_ < CH; ++u_)                 \
                NXT[u_] = (WP)[(size_t)(((C) + 2) * CH + u_) * 256];          \
        }                                                                     \
        _Pragma("unroll") for (int u_ = 0; u_ < CH; u_ += 4) {                \
            const float4 hv_ = (HP4)[((C) * CH + u_) >> 2];                   \
            A0 = fmaf(hv_.x, CUR[u_ + 0].x, A0); A1 = fmaf(hv_.x, CUR[u_ + 0].y, A1); \
            A0 = fmaf(hv_.y, CUR[u_ + 1].x, A0); A1 = fmaf(hv_.y, CUR[u_ + 1].y, A1); \
            A0 = fmaf(hv_.z, CUR[u_ + 2].x, A0); A1 = fmaf(hv_.z, CUR[u_ + 2].y, A1); \
            A0 = fmaf(hv_.w, CUR[u_ + 3].x, A0); A1 = fmaf(hv_.w, CUR[u_ + 3].y, A1); \
        }                                                                     \
    }

template <bool PRE>
__global__ __launch_bounds__(256, 1) void rnn_stream(
        const float* __restrict__ Whh,
        const float* __restrict__ xw_or_x,   // PRE: xw[b][t][j]; else x[b][t][i]
        const float* __restrict__ Wxh,       // fallback only
        const float* __restrict__ bias_h,    // fallback only
        float* __restrict__ hlast) {
    const int b = blockIdx.x;
    const int tid = threadIdx.x;
    const int j0 = tid * 2;                  // thread owns columns j0, j0+1

    __shared__ float hs[2][Hn];              // double-buffered hidden state
    __shared__ float xr[2][In];              // fallback: staged x rows

    hs[0][j0] = 0.f;                         // h_0 = 0
    hs[0][j0 + 1] = 0.f;
    float bh0 = 0.f, bh1 = 0.f;
    if constexpr (!PRE) {
        xr[0][tid] = xw_or_x[(size_t)b * Sn * In + tid];   // row 0 (In==256)
        bh0 = bias_h[j0];
        bh1 = bias_h[j0 + 1];
    }
    __syncthreads();

    const float2* wp = (const float2*)Whh + tid;   // element k*256 + tid

    float2 wa[CH], wb[CH], wc[CH], wd[CH];
    if constexpr (PRE) {
        // steady-state priming: chunk0 -> wa, chunk1 -> wb (persists across steps)
#pragma unroll
        for (int u = 0; u < CH; ++u) {
            wa[u] = wp[(size_t)(0 * CH + u) * 256];
            wb[u] = wp[(size_t)(1 * CH + u) * 256];
        }
    }

    float hn0 = 0.f, hn1 = 0.f;

    for (int t = 0; t < Sn; ++t) {
        const int p = t & 1;
        const float4* h4 = (const float4*)&hs[p][0];
        float a0 = 0.f, a1 = 0.f;
        float xw0, xw1;

        if constexpr (PRE) {
            // xw load issued before the chain; consumed ~3400cy later
            const float2 xv = *(const float2*)(xw_or_x + ((size_t)b * Sn + t) * Hn + j0);
            // hacc: k = 0..511 ascending, single acc per column (exact order).
            // 16 chunks, 4-buffer rotation, wrap prefetch distance 2:
            // after the step, wa=chunk0, wb=chunk1 again (loads for t+1
            // already in flight during t's tail).
            for (int cc = 0; cc < 16; cc += 4) {
                CHUNKW(wp, h4, wa, wc, cc + 0);
                CHUNKW(wp, h4, wb, wd, cc + 1);
                CHUNKW(wp, h4, wc, wa, cc + 2);
                CHUNKW(wp, h4, wd, wb, cc + 3);
            }
            xw0 = xv.x;
            xw1 = xv.y;
        } else {
            // stage-next-x load issued early (written to LDS after chains)
            float xnext = 0.f;
            if (t + 1 < Sn)
                xnext = xw_or_x[((size_t)b * Sn + t + 1) * In + tid];

            // xacc: i = 0..255 ascending over streamed Wxh (exact order)
            const float2* wxp = (const float2*)Wxh + tid;
            const float4* x4 = (const float4*)&xr[p][0];
            float xa0 = 0.f, xa1 = 0.f;
#pragma unroll
            for (int u = 0; u < CH; ++u) {
                wa[u] = wxp[(size_t)u * 256];
                wb[u] = wxp[(size_t)(CH + u) * 256];
            }
            CHUNKL(wxp, x4, wa, wc, 0, 8, xa0, xa1);
            CHUNKL(wxp, x4, wb, wd, 1, 8, xa0, xa1);
            CHUNKL(wxp, x4, wc, wa, 2, 8, xa0, xa1);
            CHUNKL(wxp, x4, wd, wb, 3, 8, xa0, xa1);
            CHUNKL(wxp, x4, wa, wc, 4, 8, xa0, xa1);
            CHUNKL(wxp, x4, wb, wd, 5, 8, xa0, xa1);
            CHUNKL(wxp, x4, wc, wa, 6, 8, xa0, xa1);
            CHUNKL(wxp, x4, wd, wb, 7, 8, xa0, xa1);
            xw0 = xa0 + bh0;
            xw1 = xa1 + bh1;

            // hacc: 16 chunks over Whh, linear prefetch
#pragma unroll
            for (int u = 0; u < CH; ++u) {
                wa[u] = wp[(size_t)u * 256];
                wb[u] = wp[(size_t)(CH + u) * 256];
            }
            for (int cc = 0; cc < 16; cc += 4) {
                CHUNKL(wp, h4, wa, wc, cc + 0, 16, a0, a1);
                CHUNKL(wp, h4, wb, wd, cc + 1, 16, a0, a1);
                CHUNKL(wp, h4, wc, wa, cc + 2, 16, a0, a1);
                CHUNKL(wp, h4, wd, wb, cc + 3, 16, a0, a1);
            }
            if (t + 1 < Sn) xr[1 - p][tid] = xnext;
        }

        const float u0 = xw0 + a0;           // exact association: xw + hacc
        const float u1 = xw1 + a1;
        hn0 = xla_tanh(u0);
        hn1 = xla_tanh(u1);
        hs[1 - p][j0] = hn0;                 // next-step h (other buffer)
        hs[1 - p][j0 + 1] = hn1;
        __syncthreads();                     // one barrier per step
    }

    hlast[(size_t)b * Hn + j0] = hn0;
    hlast[(size_t)b * Hn + j0 + 1] = hn1;
}

// ---------------------------------------------------------------------------
// y[b][o] = fma-chain_k(h_last[b][k]*Why[k][o]) + bias_y[o]  (unchanged, exact)
// ---------------------------------------------------------------------------
__global__ __launch_bounds__(256) void out_gemm(const float* __restrict__ hlast,
                                                const float* __restrict__ Why,
                                                const float* __restrict__ bias_y,
                                                float* __restrict__ y) {
    const int b = blockIdx.x, o = threadIdx.x;
    __shared__ float hs[Hn];
    hs[o] = hlast[(size_t)b * Hn + o];
    hs[o + 256] = hlast[(size_t)b * Hn + o + 256];
    __syncthreads();
    float acc = 0.0f;
#pragma unroll 8
    for (int k = 0; k < Hn; ++k)
        acc = fmaf(hs[k], Why[(size_t)k * On + o], acc);
    y[(size_t)b * On + o] = acc + bias_y[o];
}

// ---------------------------------------------------------------------------
extern "C" void kernel_launch(void* const* d_in, const int* in_sizes, int n_in,
                              void* d_out, int out_size, void* d_ws, size_t ws_size,
                              hipStream_t stream) {
    // Map inputs by size (x=33554432, Whh=262144, Wxh/Why=131072 in order,
    // bias_h=512, bias_y=256).
    const float *x = nullptr, *Wxh = nullptr, *Whh = nullptr, *Why = nullptr,
                *bias_h = nullptr, *bias_y = nullptr;
    for (int i = 0; i < n_in; ++i) {
        const float* p = (const float*)d_in[i];
        const int sz = in_sizes[i];
        if (sz == Bn * Sn * In) x = p;
        else if (sz == Hn * Hn) Whh = p;
        else if (sz == In * Hn) { if (!Wxh) Wxh = p; else Why = p; }
        else if (sz == Hn) bias_h = p;
        else if (sz == On) bias_y = p;
    }
    float* y = (float*)d_out;

    // workspace: hlast (128 KB) + xw (64*2048*512 f32 = 256 MB, if it fits).
    // No memset needed: both regions are fully written before being read.
    char* ws = (char*)d_ws;
    float* hlast = (float*)ws;
    const size_t hlast_bytes = (size_t)Bn * Hn * sizeof(float);
    float* xw = (float*)(ws + hlast_bytes);
    const size_t xw_bytes = (size_t)Bn * Sn * Hn * sizeof(float);

    if (ws_size >= hlast_bytes + xw_bytes) {
        xw_gemm<<<dim3(Bn * (Sn / TT)), dim3(512), 0, stream>>>(x, Wxh, bias_h, xw);
        rnn_stream<true><<<dim3(Bn), dim3(256), 0, stream>>>(Whh, xw, nullptr,
                                                             nullptr, hlast);
    } else {
        rnn_stream<false><<<dim3(Bn), dim3(256), 0, stream>>>(Whh, x, Wxh,
                                                              bias_h, hlast);
    }
    out_gemm<<<dim3(Bn), dim3(On), 0, stream>>>(hlast, Why, bias_y, y);
}